// Round 8
// baseline (583.011 us; speedup 1.0000x reference)
//
#include <hip/hip_runtime.h>
#include <hip/hip_bf16.h>

// Problem constants
#define BDIM 8
#define TDIM 256
#define UDIM 64
#define HDIM 640
#define VDIM 1024
#define MDIM (BDIM * TDIM * UDIM)   // 131072

#define BK 32
#define NT (HDIM / BK)              // 20 K-steps

typedef __attribute__((ext_vector_type(8))) short short8;   // 8 bf16 (16B)
typedef __attribute__((ext_vector_type(4))) float f32x4;

__device__ __forceinline__ ushort f2bf(float x) {
    union { float f; unsigned int u; } v; v.f = x;
    unsigned int r = (v.u + 0x7fffu + ((v.u >> 16) & 1u)) >> 16;  // RNE
    return (ushort)r;
}

// Prep 1: W (V x H fp32) -> bf16
__global__ void cvt_w_kernel(const float* __restrict__ W, ushort* __restrict__ Wb) {
    int i = (blockIdx.x * 256 + threadIdx.x) * 4;
    f32x4 w = *(const f32x4*)(W + i);
    ushort4 o;
    o.x = f2bf(w[0]); o.y = f2bf(w[1]); o.z = f2bf(w[2]); o.w = f2bf(w[3]);
    *(ushort4*)(Wb + i) = o;
}

// Prep 2: h[m][k] = relu(f[b][t][k] + p[b][u][k]) as bf16
__global__ __launch_bounds__(256) void build_h_kernel(
    const float* __restrict__ f, const float* __restrict__ p,
    ushort* __restrict__ h)
{
    const int tid = threadIdx.x;
    const int row = (blockIdx.x << 5) + (tid >> 3);
    const int j0  = tid & 7;
    const int b = row >> 14;
    const int t = (row >> 6) & (TDIM - 1);
    const int u = row & (UDIM - 1);
    const float* frow = f + (size_t)(b * TDIM + t) * HDIM;
    const float* prow = p + (size_t)(b * UDIM + u) * HDIM;
    ushort* hrow = h + (size_t)row * HDIM;
    #pragma unroll
    for (int it = 0; it < HDIM / 64; ++it) {
        const int k = (j0 + it * 8) * 8;
        f32x4 f0 = *(const f32x4*)(frow + k);
        f32x4 f1 = *(const f32x4*)(frow + k + 4);
        f32x4 p0 = *(const f32x4*)(prow + k);
        f32x4 p1 = *(const f32x4*)(prow + k + 4);
        short8 hv;
        #pragma unroll
        for (int e = 0; e < 4; ++e) {
            float a0 = fmaxf(f0[e] + p0[e], 0.0f);
            float a1 = fmaxf(f1[e] + p1[e], 0.0f);
            hv[e]     = (short)f2bf(a0);
            hv[e + 4] = (short)f2bf(a1);
        }
        *(short8*)(hrow + k) = hv;
    }
}

// ==================== register-direct GEMM (no LDS, no barriers) =========
// Per-wave output tile 128m x 64n, acc 8x4 f32x4. Block = 4 waves side-by-
// side in n => block tile 128 x 256. All waves read the SAME A rows =>
// L1 services 3 of 4 A-readers; B (W) slice is L2-resident (<=1.25MB/XCD).
// K-loop: double-banked register fragments, prefetch distance 1. The
// compiler emits counted per-register vmcnt waits (register destinations,
// no barriers => no vmcnt(0) drain anywhere). Waves fully independent.
__global__ __launch_bounds__(256, 2) void hgemm_reg_kernel(
    const ushort* __restrict__ h,     // (M,H) bf16
    const ushort* __restrict__ Wb,    // (V,H) bf16
    const float* __restrict__ bias,   // (V)
    float* __restrict__ out)          // (M,V) fp32
{
    const int tid  = threadIdx.x;
    const int lane = tid & 63;
    const int wave = tid >> 6;   // 0..3 -> n-quarter

    // Bijective XCD swizzle: 4096 blocks (%8==0). XCD x gets works
    // [x*512,(x+1)*512); consecutive works walk the 4 ntiles of one mtile
    // -> A rows L2/L1-hot, per-XCD W slice resident.
    const int bid   = blockIdx.x;
    const int work  = (bid & 7) * 512 + (bid >> 3);
    const int mtile = work >> 2;        // 0..1023
    const int ntile = work & 3;         // 0..3
    const int m0 = mtile * 128;
    const int v0 = ntile * 256 + wave * 64;

    const int lr = lane & 15;           // fragment row within 16
    const int lk = (lane >> 4) * 8;     // k element offset within BK=32

    // Per-lane element offsets (32-bit; max 131071*640+632 < 2^27)
    int aoffs[8], boffs[4];
    #pragma unroll
    for (int mi = 0; mi < 8; ++mi)
        aoffs[mi] = (m0 + mi * 16 + lr) * HDIM + lk;
    #pragma unroll
    for (int ni = 0; ni < 4; ++ni)
        boffs[ni] = (v0 + ni * 16 + lr) * HDIM + lk;

    f32x4 acc[8][4];
    #pragma unroll
    for (int i = 0; i < 8; ++i)
        #pragma unroll
        for (int j = 0; j < 4; ++j)
            acc[i][j] = (f32x4)0.0f;

    short8 a0[8], b0[4], a1[8], b1[4];

#define LOADF(A, B, kt) do {                                                   \
        const int koff_ = (kt) * BK;                                           \
        _Pragma("unroll")                                                      \
        for (int i_ = 0; i_ < 8; ++i_)                                         \
            (A)[i_] = *(const short8*)(h + aoffs[i_] + koff_);                 \
        _Pragma("unroll")                                                      \
        for (int i_ = 0; i_ < 4; ++i_)                                         \
            (B)[i_] = *(const short8*)(Wb + boffs[i_] + koff_);                \
    } while (0)

#define MFMAS(A, B) do {                                                       \
        __builtin_amdgcn_s_setprio(1);                                         \
        _Pragma("unroll")                                                      \
        for (int mi_ = 0; mi_ < 8; ++mi_)                                      \
            _Pragma("unroll")                                                  \
            for (int ni_ = 0; ni_ < 4; ++ni_)                                  \
                acc[mi_][ni_] = __builtin_amdgcn_mfma_f32_16x16x32_bf16(       \
                    (A)[mi_], (B)[ni_], acc[mi_][ni_], 0, 0, 0);               \
        __builtin_amdgcn_s_setprio(0);                                         \
    } while (0)

    LOADF(a0, b0, 0);
    #pragma unroll 1
    for (int t = 0; t < NT; t += 2) {
        LOADF(a1, b1, t + 1);            // t+1 <= 19 always (NT even)
        MFMAS(a0, b0);                   // compiler waits only on bank0
        if (t + 2 < NT) LOADF(a0, b0, t + 2);
        MFMAS(a1, b1);
    }
#undef LOADF
#undef MFMAS

    // Epilogue: C/D col = lane&15, row = (lane>>4)*4 + reg
    #pragma unroll
    for (int ni = 0; ni < 4; ++ni) {
        const int col = v0 + ni * 16 + lr;
        const float bv = bias[col];
        #pragma unroll
        for (int mi = 0; mi < 8; ++mi) {
            const int rbase = m0 + mi * 16 + ((lane >> 4) << 2);
            #pragma unroll
            for (int reg = 0; reg < 4; ++reg) {
                out[(size_t)(rbase + reg) * VDIM + col] = acc[mi][ni][reg] + bv;
            }
        }
    }
}

#define GLDS(srcptr, ldsptr)                                                   \
    __builtin_amdgcn_global_load_lds(                                          \
        (const __attribute__((address_space(1))) void*)(srcptr),               \
        (__attribute__((address_space(3))) void*)(ldsptr), 16, 0, 0)

// ---------------- fallback fused kernel (round-1 verified) ----------------
template <bool USE_WB>
__global__ __launch_bounds__(256) void joint_gemm_kernel(
    const float* __restrict__ f, const float* __restrict__ p,
    const float* __restrict__ Wf, const ushort* __restrict__ Wb,
    const float* __restrict__ bias, float* __restrict__ out)
{
    __shared__ ushort Alds[128 * 64];
    __shared__ ushort Blds[128 * 64];

    const int tid  = threadIdx.x;
    const int lane = tid & 63;
    const int wave = tid >> 6;
    const int wm   = wave >> 1;
    const int wn   = wave & 1;

    const int bid   = blockIdx.x;
    const int work  = (bid & 7) * 1024 + (bid >> 3);
    const int mtile = work >> 3;
    const int ntile = work & 7;
    const int m0 = mtile * 128;
    const int v0 = ntile * 128;

    const int b  = m0 >> 14;
    const int t0 = (m0 >> 6) & (TDIM - 1);

    const float*  fbase = f + (size_t)(b * TDIM + t0) * HDIM;
    const float*  pbase = p + (size_t)b * UDIM * HDIM;
    const ushort* wbbase = Wb + (size_t)v0 * HDIM;
    const float*  wfbase = Wf + (size_t)v0 * HDIM;

    f32x4 acc[4][4];
    #pragma unroll
    for (int i = 0; i < 4; ++i)
        #pragma unroll
        for (int j = 0; j < 4; ++j)
            acc[i][j] = (f32x4)0.0f;

    for (int kt = 0; kt < HDIM / 64; ++kt) {
        const int k0 = kt * 64;
        __syncthreads();

        if (USE_WB) {
            #pragma unroll
            for (int it = 0; it < 4; ++it) {
                const int c   = it * 256 + tid;
                const int row = c >> 3;
                const int j   = c & 7;
                const ushort* src = wbbase + row * HDIM + k0 + ((j ^ (row & 7)) << 3);
                GLDS(src, &Blds[(it * 256 + wave * 64) * 8]);
            }
        } else {
            #pragma unroll
            for (int it = 0; it < 4; ++it) {
                const int c   = it * 256 + tid;
                const int row = c >> 3;
                const int j   = c & 7;
                const float* wp = wfbase + row * HDIM + k0 + j * 8;
                f32x4 w0 = *(const f32x4*)wp;
                f32x4 w1 = *(const f32x4*)(wp + 4);
                short8 wv;
                #pragma unroll
                for (int e = 0; e < 4; ++e) {
                    wv[e]     = (short)f2bf(w0[e]);
                    wv[e + 4] = (short)f2bf(w1[e]);
                }
                *(short8*)(&Blds[(row * 8 + (j ^ (row & 7))) * 8]) = wv;
            }
        }

        #pragma unroll
        for (int it = 0; it < 4; ++it) {
            const int c   = it * 256 + tid;
            const int row = c >> 3;
            const int j   = c & 7;
            const float* fp_ = fbase + (row >> 6) * HDIM + k0 + j * 8;
            const float* pp_ = pbase + (row & 63) * HDIM + k0 + j * 8;
            f32x4 f0 = *(const f32x4*)fp_;
            f32x4 f1 = *(const f32x4*)(fp_ + 4);
            f32x4 p0 = *(const f32x4*)pp_;
            f32x4 p1 = *(const f32x4*)(pp_ + 4);
            short8 hv;
            #pragma unroll
            for (int e = 0; e < 4; ++e) {
                float a0 = fmaxf(f0[e] + p0[e], 0.0f);
                float a1 = fmaxf(f1[e] + p1[e], 0.0f);
                hv[e]     = (short)f2bf(a0);
                hv[e + 4] = (short)f2bf(a1);
            }
            *(short8*)(&Alds[(row * 8 + (j ^ (row & 7))) * 8]) = hv;
        }

        __syncthreads();

        #pragma unroll
        for (int ks = 0; ks < 2; ++ks) {
            short8 afr[4], bfr[4];
            #pragma unroll
            for (int mi = 0; mi < 4; ++mi) {
                const int r = wm * 64 + mi * 16 + (lane & 15);
                const int j = ks * 4 + (lane >> 4);
                afr[mi] = *(const short8*)(&Alds[(r * 8 + (j ^ (r & 7))) * 8]);
            }
            #pragma unroll
            for (int ni = 0; ni < 4; ++ni) {
                const int r = wn * 64 + ni * 16 + (lane & 15);
                const int j = ks * 4 + (lane >> 4);
                bfr[ni] = *(const short8*)(&Blds[(r * 8 + (j ^ (r & 7))) * 8]);
            }
            #pragma unroll
            for (int mi = 0; mi < 4; ++mi)
                #pragma unroll
                for (int ni = 0; ni < 4; ++ni)
                    acc[mi][ni] = __builtin_amdgcn_mfma_f32_16x16x32_bf16(
                        afr[mi], bfr[ni], acc[mi][ni], 0, 0, 0);
        }
    }

    #pragma unroll
    for (int ni = 0; ni < 4; ++ni) {
        const int col = v0 + wn * 64 + ni * 16 + (lane & 15);
        const float bv = bias[col];
        #pragma unroll
        for (int mi = 0; mi < 4; ++mi) {
            const int rbase = m0 + wm * 64 + mi * 16 + ((lane >> 4) << 2);
            #pragma unroll
            for (int reg = 0; reg < 4; ++reg) {
                out[(size_t)(rbase + reg) * VDIM + col] = acc[mi][ni][reg] + bv;
            }
        }
    }
}

extern "C" void kernel_launch(void* const* d_in, const int* in_sizes, int n_in,
                              void* d_out, int out_size, void* d_ws, size_t ws_size,
                              hipStream_t stream) {
    const float* f    = (const float*)d_in[0];   // (8,256,640)
    const float* p    = (const float*)d_in[1];   // (8,64,640)
    const float* W    = (const float*)d_in[2];   // (1024,640)
    const float* bias = (const float*)d_in[3];   // (1024)
    float* out = (float*)d_out;                  // (8,256,64,1024) fp32

    const size_t wb_bytes = (size_t)VDIM * HDIM * sizeof(ushort);   // 1.25 MB
    const size_t h_bytes  = (size_t)MDIM * HDIM * sizeof(ushort);   // 160 MB

    if (ws_size >= wb_bytes + h_bytes) {
        ushort* Wb = (ushort*)d_ws;
        ushort* h  = (ushort*)((char*)d_ws + wb_bytes);
        cvt_w_kernel<<<(VDIM * HDIM) / 1024, 256, 0, stream>>>(W, Wb);
        build_h_kernel<<<MDIM / 32, 256, 0, stream>>>(f, p, h);
        const int grid = (MDIM / 128) * (VDIM / 256);   // 4096 blocks
        hgemm_reg_kernel<<<grid, 256, 0, stream>>>(h, Wb, bias, out);
    } else if (ws_size >= wb_bytes) {
        ushort* Wb = (ushort*)d_ws;
        cvt_w_kernel<<<(VDIM * HDIM) / 1024, 256, 0, stream>>>(W, Wb);
        joint_gemm_kernel<true><<<(MDIM / 128) * (VDIM / 128), 256, 0, stream>>>(
            f, p, W, Wb, bias, out);
    } else {
        joint_gemm_kernel<false><<<(MDIM / 128) * (VDIM / 128), 256, 0, stream>>>(
            f, p, W, nullptr, bias, out);
    }
}

// Round 10
// 412.714 us; speedup vs baseline: 1.4126x; 1.4126x over previous
//
#include <hip/hip_runtime.h>
#include <hip/hip_bf16.h>

// Problem constants
#define BDIM 8
#define TDIM 256
#define UDIM 64
#define HDIM 640
#define VDIM 1024
#define MDIM (BDIM * TDIM * UDIM)   // 131072

#define BK 32
#define NT (HDIM / BK)              // 20 K-steps
#define NKC (HDIM / 8)              // 80 k-chunks per row

typedef __attribute__((ext_vector_type(8))) short short8;   // 8 bf16 (16B)
typedef __attribute__((ext_vector_type(4))) float f32x4;

__device__ __forceinline__ ushort f2bf(float x) {
    union { float f; unsigned int u; } v; v.f = x;
    unsigned int r = (v.u + 0x7fffu + ((v.u >> 16) & 1u)) >> 16;  // RNE
    return (ushort)r;
}

// ---------------------------------------------------------------------------
// Fragment-tiled layout: element (row, k) of a (R x 640) matrix lives at
//   chunk c = (row>>4)*80 + (k>>3);  ushort index = c*128 + (row&15)*8 + (k&7)
// A wave's 16x32 MFMA fragment (rows g*16..+15, k = kc0*8..+31) is the 1KB
// span [(g*80+kc0)*128, +512) read as base + lane*8 -> ONE fully coalesced
// global_load_dwordx4 per lane (lane = hi*16+lr holds row g*16+lr,
// k=(kc0+hi)*8+e — exactly the 16x16x32 A/B fragment mapping).
// ---------------------------------------------------------------------------

// Prep 1: W (V x H fp32, row-major) -> fragment-tiled bf16.
// One thread per 16B chunk-row: VDIM*HDIM/8 = 81920 threads = 320 blocks.
__global__ __launch_bounds__(256) void cvt_w_tiled_kernel(
    const float* __restrict__ W, ushort* __restrict__ Wt)
{
    const int c  = blockIdx.x * 256 + threadIdx.x;
    const int lr = c & 15;
    const int q  = c >> 4;
    const int kc = q % NKC;
    const int g  = q / NKC;
    const int v  = g * 16 + lr;
    const float* src = W + (size_t)v * HDIM + kc * 8;
    f32x4 w0 = *(const f32x4*)src;
    f32x4 w1 = *(const f32x4*)(src + 4);
    short8 o;
    #pragma unroll
    for (int e = 0; e < 4; ++e) {
        o[e]     = (short)f2bf(w0[e]);
        o[e + 4] = (short)f2bf(w1[e]);
    }
    *(short8*)(Wt + (size_t)c * 8) = o;    // coalesced 16B/thread
}

// Prep 2: h = relu(f+p), fragment-tiled.
// One thread per 16B chunk-row: MDIM*HDIM/8 = 10,485,760 threads = 40960
// blocks (ROUND-9 BUG: grid was 16x too small; fixed in launch below).
__global__ __launch_bounds__(256) void build_h_tiled_kernel(
    const float* __restrict__ f, const float* __restrict__ p,
    ushort* __restrict__ ht)
{
    const int c  = blockIdx.x * 256 + threadIdx.x;
    const int lr = c & 15;
    const int q  = c >> 4;
    const int kc = q % NKC;
    const int g  = q / NKC;
    const int m  = g * 16 + lr;
    const int b  = m >> 14;
    const int t  = (m >> 6) & (TDIM - 1);
    const int u  = m & (UDIM - 1);
    const int k  = kc * 8;
    const float* fr = f + (size_t)(b * TDIM + t) * HDIM + k;
    const float* pr = p + (size_t)(b * UDIM + u) * HDIM + k;
    f32x4 f0 = *(const f32x4*)fr;
    f32x4 f1 = *(const f32x4*)(fr + 4);
    f32x4 p0 = *(const f32x4*)pr;
    f32x4 p1 = *(const f32x4*)(pr + 4);
    short8 o;
    #pragma unroll
    for (int e = 0; e < 4; ++e) {
        float a0 = fmaxf(f0[e] + p0[e], 0.0f);
        float a1 = fmaxf(f1[e] + p1[e], 0.0f);
        o[e]     = (short)f2bf(a0);
        o[e + 4] = (short)f2bf(a1);
    }
    *(short8*)(ht + (size_t)c * 8) = o;    // coalesced 16B/thread
}

// ================= register-direct GEMM, fragment-tiled inputs ============
// No LDS, no barriers, no syncthreads. 4 waves (2 wm x 2 wn); per-wave tile
// 128m x 64n (block 256x128), acc 8x4 f32x4. Per K-tile: 12 coalesced 1KB
// loads (12KB) vs 32 MFMA (~515 SIMD-cyc) -> per-CU VMEM demand ~93 B/cy,
// near the ~64 B/cy TA/L2 ceiling; MFMA floor 69us, VMEM floor ~100us.
// Double-banked fragments, prefetch distance 1; compiler emits counted
// per-register vmcnt (no drains anywhere); waves fully independent.
__global__ __launch_bounds__(256, 2) void hgemm_regT_kernel(
    const ushort* __restrict__ ht,    // fragment-tiled h
    const ushort* __restrict__ Wt,    // fragment-tiled W
    const float* __restrict__ bias,   // (V)
    float* __restrict__ out)          // (M,V) fp32
{
    const int tid  = threadIdx.x;
    const int lane = tid & 63;
    const int wave = tid >> 6;   // 0..3
    const int wm   = wave >> 1;  // 0..1 -> 128-row half
    const int wn   = wave & 1;   // 0..1 -> 64-col half

    // Bijective XCD swizzle: 4096 blocks (%8==0). XCD x runs works
    // [x*512,(x+1)*512): 8 ntiles of one mtile consecutive -> each h-panel
    // (320KB) HBM-fetched once per XCD, Wt (1.25MB) L2-resident.
    const int bid   = blockIdx.x;
    const int work  = (bid & 7) * 512 + (bid >> 3);
    const int mtile = work >> 3;        // 0..511
    const int ntile = work & 7;         // 0..7
    const int m0 = mtile * 256;
    const int v0 = ntile * 128;

    const int gA = mtile * 16 + wm * 8;   // wave's 8 m-groups
    const int gB = ntile * 8 + wn * 4;    // wave's 4 v-groups
    const int la = lane * 8;

    // Fragment base offsets (ushort idx); K-tile t adds t*512 (=4 chunks).
    int abase[8], bbase[4];
    #pragma unroll
    for (int mi = 0; mi < 8; ++mi) abase[mi] = (gA + mi) * (NKC * 128) + la;
    #pragma unroll
    for (int ni = 0; ni < 4; ++ni) bbase[ni] = (gB + ni) * (NKC * 128) + la;

    f32x4 acc[8][4];
    #pragma unroll
    for (int i = 0; i < 8; ++i)
        #pragma unroll
        for (int j = 0; j < 4; ++j)
            acc[i][j] = (f32x4)0.0f;

    short8 a0[8], b0[4], a1[8], b1[4];

#define LOADF(A, B, kt) do {                                                   \
        const int ko_ = (kt) * 512;                                            \
        _Pragma("unroll")                                                      \
        for (int i_ = 0; i_ < 8; ++i_)                                         \
            (A)[i_] = *(const short8*)(ht + abase[i_] + ko_);                  \
        _Pragma("unroll")                                                      \
        for (int i_ = 0; i_ < 4; ++i_)                                         \
            (B)[i_] = *(const short8*)(Wt + bbase[i_] + ko_);                  \
    } while (0)

#define MFMAS(A, B) do {                                                       \
        __builtin_amdgcn_s_setprio(1);                                         \
        _Pragma("unroll")                                                      \
        for (int mi_ = 0; mi_ < 8; ++mi_)                                      \
            _Pragma("unroll")                                                  \
            for (int ni_ = 0; ni_ < 4; ++ni_)                                  \
                acc[mi_][ni_] = __builtin_amdgcn_mfma_f32_16x16x32_bf16(       \
                    (A)[mi_], (B)[ni_], acc[mi_][ni_], 0, 0, 0);               \
        __builtin_amdgcn_s_setprio(0);                                         \
    } while (0)

    LOADF(a0, b0, 0);
    #pragma unroll 1
    for (int t = 0; t < NT; t += 2) {
        LOADF(a1, b1, t + 1);            // NT even -> t+1 always valid
        MFMAS(a0, b0);                   // waits only on bank-0 regs
        if (t + 2 < NT) LOADF(a0, b0, t + 2);
        MFMAS(a1, b1);
    }
#undef LOADF
#undef MFMAS

    // Epilogue: C/D col = lane&15, row = (lane>>4)*4 + reg
    const int lr = lane & 15;
    #pragma unroll
    for (int ni = 0; ni < 4; ++ni) {
        const int col = v0 + wn * 64 + ni * 16 + lr;
        const float bv = bias[col];
        #pragma unroll
        for (int mi = 0; mi < 8; ++mi) {
            const int rbase = m0 + wm * 128 + mi * 16 + ((lane >> 4) << 2);
            #pragma unroll
            for (int reg = 0; reg < 4; ++reg) {
                out[(size_t)(rbase + reg) * VDIM + col] = acc[mi][ni][reg] + bv;
            }
        }
    }
}

// ---------------- fallback path (round-1 verified, linear layouts) ---------
__global__ void cvt_w_kernel(const float* __restrict__ W, ushort* __restrict__ Wb) {
    int i = (blockIdx.x * 256 + threadIdx.x) * 4;
    f32x4 w = *(const f32x4*)(W + i);
    ushort4 o;
    o.x = f2bf(w[0]); o.y = f2bf(w[1]); o.z = f2bf(w[2]); o.w = f2bf(w[3]);
    *(ushort4*)(Wb + i) = o;
}

#define GLDS(srcptr, ldsptr)                                                   \
    __builtin_amdgcn_global_load_lds(                                          \
        (const __attribute__((address_space(1))) void*)(srcptr),               \
        (__attribute__((address_space(3))) void*)(ldsptr), 16, 0, 0)

template <bool USE_WB>
__global__ __launch_bounds__(256) void joint_gemm_kernel(
    const float* __restrict__ f, const float* __restrict__ p,
    const float* __restrict__ Wf, const ushort* __restrict__ Wb,
    const float* __restrict__ bias, float* __restrict__ out)
{
    __shared__ ushort Alds[128 * 64];
    __shared__ ushort Blds[128 * 64];

    const int tid  = threadIdx.x;
    const int lane = tid & 63;
    const int wave = tid >> 6;
    const int wm   = wave >> 1;
    const int wn   = wave & 1;

    const int bid   = blockIdx.x;
    const int work  = (bid & 7) * 1024 + (bid >> 3);
    const int mtile = work >> 3;
    const int ntile = work & 7;
    const int m0 = mtile * 128;
    const int v0 = ntile * 128;

    const int b  = m0 >> 14;
    const int t0 = (m0 >> 6) & (TDIM - 1);

    const float*  fbase = f + (size_t)(b * TDIM + t0) * HDIM;
    const float*  pbase = p + (size_t)b * UDIM * HDIM;
    const ushort* wbbase = Wb + (size_t)v0 * HDIM;
    const float*  wfbase = Wf + (size_t)v0 * HDIM;

    f32x4 acc[4][4];
    #pragma unroll
    for (int i = 0; i < 4; ++i)
        #pragma unroll
        for (int j = 0; j < 4; ++j)
            acc[i][j] = (f32x4)0.0f;

    for (int kt = 0; kt < HDIM / 64; ++kt) {
        const int k0 = kt * 64;
        __syncthreads();

        if (USE_WB) {
            #pragma unroll
            for (int it = 0; it < 4; ++it) {
                const int c   = it * 256 + tid;
                const int row = c >> 3;
                const int j   = c & 7;
                const ushort* src = wbbase + row * HDIM + k0 + ((j ^ (row & 7)) << 3);
                GLDS(src, &Blds[(it * 256 + wave * 64) * 8]);
            }
        } else {
            #pragma unroll
            for (int it = 0; it < 4; ++it) {
                const int c   = it * 256 + tid;
                const int row = c >> 3;
                const int j   = c & 7;
                const float* wp = wfbase + row * HDIM + k0 + j * 8;
                f32x4 w0 = *(const f32x4*)wp;
                f32x4 w1 = *(const f32x4*)(wp + 4);
                short8 wv;
                #pragma unroll
                for (int e = 0; e < 4; ++e) {
                    wv[e]     = (short)f2bf(w0[e]);
                    wv[e + 4] = (short)f2bf(w1[e]);
                }
                *(short8*)(&Blds[(row * 8 + (j ^ (row & 7))) * 8]) = wv;
            }
        }

        #pragma unroll
        for (int it = 0; it < 4; ++it) {
            const int c   = it * 256 + tid;
            const int row = c >> 3;
            const int j   = c & 7;
            const float* fp_ = fbase + (row >> 6) * HDIM + k0 + j * 8;
            const float* pp_ = pbase + (row & 63) * HDIM + k0 + j * 8;
            f32x4 f0 = *(const f32x4*)fp_;
            f32x4 f1 = *(const f32x4*)(fp_ + 4);
            f32x4 p0 = *(const f32x4*)pp_;
            f32x4 p1 = *(const f32x4*)(pp_ + 4);
            short8 hv;
            #pragma unroll
            for (int e = 0; e < 4; ++e) {
                float a0 = fmaxf(f0[e] + p0[e], 0.0f);
                float a1 = fmaxf(f1[e] + p1[e], 0.0f);
                hv[e]     = (short)f2bf(a0);
                hv[e + 4] = (short)f2bf(a1);
            }
            *(short8*)(&Alds[(row * 8 + (j ^ (row & 7))) * 8]) = hv;
        }

        __syncthreads();

        #pragma unroll
        for (int ks = 0; ks < 2; ++ks) {
            short8 afr[4], bfr[4];
            #pragma unroll
            for (int mi = 0; mi < 4; ++mi) {
                const int r = wm * 64 + mi * 16 + (lane & 15);
                const int j = ks * 4 + (lane >> 4);
                afr[mi] = *(const short8*)(&Alds[(r * 8 + (j ^ (r & 7))) * 8]);
            }
            #pragma unroll
            for (int ni = 0; ni < 4; ++ni) {
                const int r = wn * 64 + ni * 16 + (lane & 15);
                const int j = ks * 4 + (lane >> 4);
                bfr[ni] = *(const short8*)(&Blds[(r * 8 + (j ^ (r & 7))) * 8]);
            }
            #pragma unroll
            for (int mi = 0; mi < 4; ++mi)
                #pragma unroll
                for (int ni = 0; ni < 4; ++ni)
                    acc[mi][ni] = __builtin_amdgcn_mfma_f32_16x16x32_bf16(
                        afr[mi], bfr[ni], acc[mi][ni], 0, 0, 0);
        }
    }

    #pragma unroll
    for (int ni = 0; ni < 4; ++ni) {
        const int col = v0 + wn * 64 + ni * 16 + (lane & 15);
        const float bv = bias[col];
        #pragma unroll
        for (int mi = 0; mi < 4; ++mi) {
            const int rbase = m0 + wm * 64 + mi * 16 + ((lane >> 4) << 2);
            #pragma unroll
            for (int reg = 0; reg < 4; ++reg) {
                out[(size_t)(rbase + reg) * VDIM + col] = acc[mi][ni][reg] + bv;
            }
        }
    }
}

extern "C" void kernel_launch(void* const* d_in, const int* in_sizes, int n_in,
                              void* d_out, int out_size, void* d_ws, size_t ws_size,
                              hipStream_t stream) {
    const float* f    = (const float*)d_in[0];   // (8,256,640)
    const float* p    = (const float*)d_in[1];   // (8,64,640)
    const float* W    = (const float*)d_in[2];   // (1024,640)
    const float* bias = (const float*)d_in[3];   // (1024)
    float* out = (float*)d_out;                  // (8,256,64,1024) fp32

    const size_t wb_bytes = (size_t)VDIM * HDIM * sizeof(ushort);   // 1.25 MB
    const size_t h_bytes  = (size_t)MDIM * HDIM * sizeof(ushort);   // 160 MB

    if (ws_size >= wb_bytes + h_bytes) {
        ushort* Wt = (ushort*)d_ws;
        ushort* ht = (ushort*)((char*)d_ws + wb_bytes);
        // threads = elements/8 (one 16B chunk-row each)
        cvt_w_tiled_kernel<<<(VDIM * HDIM / 8) / 256, 256, 0, stream>>>(W, Wt);
        build_h_tiled_kernel<<<(MDIM / 256) * (HDIM / 8) / 8 * 8, 256, 0, stream>>>(f, p, ht);
        // ^ (MDIM*HDIM/8)/256 = 40960 blocks, written to avoid int overflow
        const int grid = (MDIM / 256) * (VDIM / 128);   // 4096
        hgemm_regT_kernel<<<grid, 256, 0, stream>>>(ht, Wt, bias, out);
    } else if (ws_size >= wb_bytes) {
        ushort* Wb = (ushort*)d_ws;
        cvt_w_kernel<<<(VDIM * HDIM) / 1024, 256, 0, stream>>>(W, Wb);
        joint_gemm_kernel<true><<<(MDIM / 128) * (VDIM / 128), 256, 0, stream>>>(
            f, p, W, Wb, bias, out);
    } else {
        joint_gemm_kernel<false><<<(MDIM / 128) * (VDIM / 128), 256, 0, stream>>>(
            f, p, W, nullptr, bias, out);
    }
}

// Round 11
// 399.496 us; speedup vs baseline: 1.4594x; 1.0331x over previous
//
#include <hip/hip_runtime.h>
#include <hip/hip_bf16.h>

// Problem constants
#define BDIM 8
#define TDIM 256
#define UDIM 64
#define HDIM 640
#define VDIM 1024
#define MDIM (BDIM * TDIM * UDIM)   // 131072

#define BK 32
#define NT (HDIM / BK)              // 20 K-steps
#define NKC (HDIM / 8)              // 80 k-chunks per row

typedef __attribute__((ext_vector_type(8))) short short8;   // 8 bf16 (16B)
typedef __attribute__((ext_vector_type(4))) float f32x4;

__device__ __forceinline__ ushort f2bf(float x) {
    union { float f; unsigned int u; } v; v.f = x;
    unsigned int r = (v.u + 0x7fffu + ((v.u >> 16) & 1u)) >> 16;  // RNE
    return (ushort)r;
}

// ---------------------------------------------------------------------------
// Fragment-tiled layout (verified round 10): element (row,k) lives at
//   chunk c = (row>>4)*80 + (k>>3); ushort idx = c*128 + (row&15)*8 + (k&7)
// A wave's 16x32 MFMA fragment = 1KB span read as base + lane*8 -> ONE fully
// coalesced global_load_dwordx4 (lane hi*16+lr -> row lr, k-chunk kc0+hi).
// ---------------------------------------------------------------------------

// Prep 1: W (V x H fp32) -> fragment-tiled bf16. 81920 threads.
__global__ __launch_bounds__(256) void cvt_w_tiled_kernel(
    const float* __restrict__ W, ushort* __restrict__ Wt)
{
    const int c  = blockIdx.x * 256 + threadIdx.x;
    const int lr = c & 15;
    const int q  = c >> 4;
    const int kc = q % NKC;
    const int g  = q / NKC;
    const int v  = g * 16 + lr;
    const float* src = W + (size_t)v * HDIM + kc * 8;
    f32x4 w0 = *(const f32x4*)src;
    f32x4 w1 = *(const f32x4*)(src + 4);
    short8 o;
    #pragma unroll
    for (int e = 0; e < 4; ++e) {
        o[e]     = (short)f2bf(w0[e]);
        o[e + 4] = (short)f2bf(w1[e]);
    }
    *(short8*)(Wt + (size_t)c * 8) = o;
}

// Prep 2: h = relu(f+p), fragment-tiled. 10,485,760 threads (verified r10).
__global__ __launch_bounds__(256) void build_h_tiled_kernel(
    const float* __restrict__ f, const float* __restrict__ p,
    ushort* __restrict__ ht)
{
    const int c  = blockIdx.x * 256 + threadIdx.x;
    const int lr = c & 15;
    const int q  = c >> 4;
    const int kc = q % NKC;
    const int g  = q / NKC;
    const int m  = g * 16 + lr;
    const int b  = m >> 14;
    const int t  = (m >> 6) & (TDIM - 1);
    const int u  = m & (UDIM - 1);
    const int k  = kc * 8;
    const float* fr = f + (size_t)(b * TDIM + t) * HDIM + k;
    const float* pr = p + (size_t)(b * UDIM + u) * HDIM + k;
    f32x4 f0 = *(const f32x4*)fr;
    f32x4 f1 = *(const f32x4*)(fr + 4);
    f32x4 p0 = *(const f32x4*)pr;
    f32x4 p1 = *(const f32x4*)(pr + 4);
    short8 o;
    #pragma unroll
    for (int e = 0; e < 4; ++e) {
        float a0 = fmaxf(f0[e] + p0[e], 0.0f);
        float a1 = fmaxf(f1[e] + p1[e], 0.0f);
        o[e]     = (short)f2bf(a0);
        o[e + 4] = (short)f2bf(a1);
    }
    *(short8*)(ht + (size_t)c * 8) = o;
}

// ============ full-width register-direct GEMM (write-streaming) ============
// Block tile 64m x 1024n (FULL V width): each block writes 64 complete,
// contiguous 4KB output rows (256KB contiguous span) -> HBM write streams
// instead of 512B/4KB-stride fragments (the ~2.2 TB/s collapse seen in
// r2-r10). h rows are read exactly ONCE (no cross-block A re-reads); Wt
// (1.25MB) is L2-resident per XCD. 8 waves (512 thr), per-wave 64m x 128n,
// acc 4x8 f32x4. No LDS, no barriers; double-banked fragment registers,
// prefetch distance 1; compiler emits counted per-register vmcnt.
__global__ __launch_bounds__(512, 2) void hgemm_wide_kernel(
    const ushort* __restrict__ ht,    // fragment-tiled h
    const ushort* __restrict__ Wt,    // fragment-tiled W
    const float* __restrict__ bias,   // (V)
    float* __restrict__ out)          // (M,V) fp32
{
    const int tid  = threadIdx.x;
    const int lane = tid & 63;
    const int wave = tid >> 6;   // 0..7 -> 128-col octant

    // Bijective XCD swizzle: 2048 blocks (%8==0). XCD x runs works
    // [x*256,(x+1)*256) = contiguous m-range -> out writes stream a
    // contiguous 64MB span per XCD; Wt stays L2-hot.
    const int bid  = blockIdx.x;
    const int work = (bid & 7) * 256 + (bid >> 3);
    const int m0   = work * 64;

    const int gA = m0 >> 4;        // 4 m-groups: gA..gA+3
    const int gB = wave * 8;       // wave's 8 v-groups
    const int la = lane * 8;

    int abase[4], bbase[8];
    #pragma unroll
    for (int mi = 0; mi < 4; ++mi) abase[mi] = (gA + mi) * (NKC * 128) + la;
    #pragma unroll
    for (int ni = 0; ni < 8; ++ni) bbase[ni] = (gB + ni) * (NKC * 128) + la;

    f32x4 acc[4][8];
    #pragma unroll
    for (int i = 0; i < 4; ++i)
        #pragma unroll
        for (int j = 0; j < 8; ++j)
            acc[i][j] = (f32x4)0.0f;

    short8 a0[4], b0[8], a1[4], b1[8];

#define LOADF(A, B, kt) do {                                                   \
        const int ko_ = (kt) * 512;                                            \
        _Pragma("unroll")                                                      \
        for (int i_ = 0; i_ < 4; ++i_)                                         \
            (A)[i_] = *(const short8*)(ht + abase[i_] + ko_);                  \
        _Pragma("unroll")                                                      \
        for (int i_ = 0; i_ < 8; ++i_)                                         \
            (B)[i_] = *(const short8*)(Wt + bbase[i_] + ko_);                  \
    } while (0)

#define MFMAS(A, B) do {                                                       \
        _Pragma("unroll")                                                      \
        for (int mi_ = 0; mi_ < 4; ++mi_)                                      \
            _Pragma("unroll")                                                  \
            for (int ni_ = 0; ni_ < 8; ++ni_)                                  \
                acc[mi_][ni_] = __builtin_amdgcn_mfma_f32_16x16x32_bf16(       \
                    (A)[mi_], (B)[ni_], acc[mi_][ni_], 0, 0, 0);               \
    } while (0)

    LOADF(a0, b0, 0);
    #pragma unroll 1
    for (int t = 0; t < NT; t += 2) {
        LOADF(a1, b1, t + 1);            // NT even -> t+1 always valid
        MFMAS(a0, b0);                   // waits only on bank-0 regs
        if (t + 2 < NT) LOADF(a0, b0, t + 2);
        MFMAS(a1, b1);
    }
#undef LOADF
#undef MFMAS

    // Epilogue: C/D col = lane&15, row = (lane>>4)*4 + reg.
    // Block writes rows m0..m0+63 completely; 8 waves tile the 4KB row.
    const int lr = lane & 15;
    #pragma unroll
    for (int ni = 0; ni < 8; ++ni) {
        const int col = wave * 128 + ni * 16 + lr;
        const float bv = bias[col];
        #pragma unroll
        for (int mi = 0; mi < 4; ++mi) {
            const int rbase = m0 + mi * 16 + ((lane >> 4) << 2);
            #pragma unroll
            for (int reg = 0; reg < 4; ++reg) {
                out[(size_t)(rbase + reg) * VDIM + col] = acc[mi][ni][reg] + bv;
            }
        }
    }
}

// ---------------- fallback path (round-1 verified, linear layouts) ---------
__global__ void cvt_w_kernel(const float* __restrict__ W, ushort* __restrict__ Wb) {
    int i = (blockIdx.x * 256 + threadIdx.x) * 4;
    f32x4 w = *(const f32x4*)(W + i);
    ushort4 o;
    o.x = f2bf(w[0]); o.y = f2bf(w[1]); o.z = f2bf(w[2]); o.w = f2bf(w[3]);
    *(ushort4*)(Wb + i) = o;
}

#define GLDS(srcptr, ldsptr)                                                   \
    __builtin_amdgcn_global_load_lds(                                          \
        (const __attribute__((address_space(1))) void*)(srcptr),               \
        (__attribute__((address_space(3))) void*)(ldsptr), 16, 0, 0)

template <bool USE_WB>
__global__ __launch_bounds__(256) void joint_gemm_kernel(
    const float* __restrict__ f, const float* __restrict__ p,
    const float* __restrict__ Wf, const ushort* __restrict__ Wb,
    const float* __restrict__ bias, float* __restrict__ out)
{
    __shared__ ushort Alds[128 * 64];
    __shared__ ushort Blds[128 * 64];

    const int tid  = threadIdx.x;
    const int lane = tid & 63;
    const int wave = tid >> 6;
    const int wm   = wave >> 1;
    const int wn   = wave & 1;

    const int bid   = blockIdx.x;
    const int work  = (bid & 7) * 1024 + (bid >> 3);
    const int mtile = work >> 3;
    const int ntile = work & 7;
    const int m0 = mtile * 128;
    const int v0 = ntile * 128;

    const int b  = m0 >> 14;
    const int t0 = (m0 >> 6) & (TDIM - 1);

    const float*  fbase = f + (size_t)(b * TDIM + t0) * HDIM;
    const float*  pbase = p + (size_t)b * UDIM * HDIM;
    const ushort* wbbase = Wb + (size_t)v0 * HDIM;
    const float*  wfbase = Wf + (size_t)v0 * HDIM;

    f32x4 acc[4][4];
    #pragma unroll
    for (int i = 0; i < 4; ++i)
        #pragma unroll
        for (int j = 0; j < 4; ++j)
            acc[i][j] = (f32x4)0.0f;

    for (int kt = 0; kt < HDIM / 64; ++kt) {
        const int k0 = kt * 64;
        __syncthreads();

        if (USE_WB) {
            #pragma unroll
            for (int it = 0; it < 4; ++it) {
                const int c   = it * 256 + tid;
                const int row = c >> 3;
                const int j   = c & 7;
                const ushort* src = wbbase + row * HDIM + k0 + ((j ^ (row & 7)) << 3);
                GLDS(src, &Blds[(it * 256 + wave * 64) * 8]);
            }
        } else {
            #pragma unroll
            for (int it = 0; it < 4; ++it) {
                const int c   = it * 256 + tid;
                const int row = c >> 3;
                const int j   = c & 7;
                const float* wp = wfbase + row * HDIM + k0 + j * 8;
                f32x4 w0 = *(const f32x4*)wp;
                f32x4 w1 = *(const f32x4*)(wp + 4);
                short8 wv;
                #pragma unroll
                for (int e = 0; e < 4; ++e) {
                    wv[e]     = (short)f2bf(w0[e]);
                    wv[e + 4] = (short)f2bf(w1[e]);
                }
                *(short8*)(&Blds[(row * 8 + (j ^ (row & 7))) * 8]) = wv;
            }
        }

        #pragma unroll
        for (int it = 0; it < 4; ++it) {
            const int c   = it * 256 + tid;
            const int row = c >> 3;
            const int j   = c & 7;
            const float* fp_ = fbase + (row >> 6) * HDIM + k0 + j * 8;
            const float* pp_ = pbase + (row & 63) * HDIM + k0 + j * 8;
            f32x4 f0 = *(const f32x4*)fp_;
            f32x4 f1 = *(const f32x4*)(fp_ + 4);
            f32x4 p0 = *(const f32x4*)pp_;
            f32x4 p1 = *(const f32x4*)(pp_ + 4);
            short8 hv;
            #pragma unroll
            for (int e = 0; e < 4; ++e) {
                float a0 = fmaxf(f0[e] + p0[e], 0.0f);
                float a1 = fmaxf(f1[e] + p1[e], 0.0f);
                hv[e]     = (short)f2bf(a0);
                hv[e + 4] = (short)f2bf(a1);
            }
            *(short8*)(&Alds[(row * 8 + (j ^ (row & 7))) * 8]) = hv;
        }

        __syncthreads();

        #pragma unroll
        for (int ks = 0; ks < 2; ++ks) {
            short8 afr[4], bfr[4];
            #pragma unroll
            for (int mi = 0; mi < 4; ++mi) {
                const int r = wm * 64 + mi * 16 + (lane & 15);
                const int j = ks * 4 + (lane >> 4);
                afr[mi] = *(const short8*)(&Alds[(r * 8 + (j ^ (r & 7))) * 8]);
            }
            #pragma unroll
            for (int ni = 0; ni < 4; ++ni) {
                const int r = wn * 64 + ni * 16 + (lane & 15);
                const int j = ks * 4 + (lane >> 4);
                bfr[ni] = *(const short8*)(&Blds[(r * 8 + (j ^ (r & 7))) * 8]);
            }
            #pragma unroll
            for (int mi = 0; mi < 4; ++mi)
                #pragma unroll
                for (int ni = 0; ni < 4; ++ni)
                    acc[mi][ni] = __builtin_amdgcn_mfma_f32_16x16x32_bf16(
                        afr[mi], bfr[ni], acc[mi][ni], 0, 0, 0);
        }
    }

    #pragma unroll
    for (int ni = 0; ni < 4; ++ni) {
        const int col = v0 + wn * 64 + ni * 16 + (lane & 15);
        const float bv = bias[col];
        #pragma unroll
        for (int mi = 0; mi < 4; ++mi) {
            const int rbase = m0 + wm * 64 + mi * 16 + ((lane >> 4) << 2);
            #pragma unroll
            for (int reg = 0; reg < 4; ++reg) {
                out[(size_t)(rbase + reg) * VDIM + col] = acc[mi][ni][reg] + bv;
            }
        }
    }
}

extern "C" void kernel_launch(void* const* d_in, const int* in_sizes, int n_in,
                              void* d_out, int out_size, void* d_ws, size_t ws_size,
                              hipStream_t stream) {
    const float* f    = (const float*)d_in[0];   // (8,256,640)
    const float* p    = (const float*)d_in[1];   // (8,64,640)
    const float* W    = (const float*)d_in[2];   // (1024,640)
    const float* bias = (const float*)d_in[3];   // (1024)
    float* out = (float*)d_out;                  // (8,256,64,1024) fp32

    const size_t wb_bytes = (size_t)VDIM * HDIM * sizeof(ushort);   // 1.25 MB
    const size_t h_bytes  = (size_t)MDIM * HDIM * sizeof(ushort);   // 160 MB

    if (ws_size >= wb_bytes + h_bytes) {
        ushort* Wt = (ushort*)d_ws;
        ushort* ht = (ushort*)((char*)d_ws + wb_bytes);
        cvt_w_tiled_kernel<<<(VDIM * HDIM / 8) / 256, 256, 0, stream>>>(W, Wt);
        build_h_tiled_kernel<<<(MDIM / 256) * (HDIM / 8), 256, 0, stream>>>(f, p, ht);
        hgemm_wide_kernel<<<MDIM / 64, 512, 0, stream>>>(ht, Wt, bias, out);
    } else if (ws_size >= wb_bytes) {
        ushort* Wb = (ushort*)d_ws;
        cvt_w_kernel<<<(VDIM * HDIM) / 1024, 256, 0, stream>>>(W, Wb);
        joint_gemm_kernel<true><<<(MDIM / 128) * (VDIM / 128), 256, 0, stream>>>(
            f, p, W, Wb, bias, out);
    } else {
        joint_gemm_kernel<false><<<(MDIM / 128) * (VDIM / 128), 256, 0, stream>>>(
            f, p, W, nullptr, bias, out);
    }
}